// Round 1
// 1018.451 us; speedup vs baseline: 1.1365x; 1.1365x over previous
//
#include <hip/hip_runtime.h>
#include <math.h>

#define BLOCK 256
#define CAP 512
#define KTOP 100
#define TEMP 5.0f
#define LAMBDA_TCS 10.0f
#define IGNORE_INDEX (-100)
#define SPEC_TH 2.5f     // speculative top-k floor; exact fallback if it fails
#define NHIST 512

// Monotonic float->uint mapping: order-preserving for all finite floats.
__device__ __forceinline__ unsigned key_of(float f) {
    unsigned u = __float_as_uint(f);
    return u ^ ((unsigned)((int)u >> 31) | 0x80000000u);
}

// Online logsumexp accumulate (2-exp branchless form).
__device__ __forceinline__ void lse_acc(float& m, float& s, float v) {
    float mn = fmaxf(m, v);
    s = s * __expf(m - mn) + __expf(v - mn);
    m = mn;
}

__device__ __forceinline__ float block_sum(float v, float* red) {
    for (int off = 32; off; off >>= 1) v += __shfl_down(v, off);
    __syncthreads();
    if ((threadIdx.x & 63) == 0) red[threadIdx.x >> 6] = v;
    __syncthreads();
    return red[0] + red[1] + red[2] + red[3];
}
__device__ __forceinline__ float block_max(float v, float* red) {
    for (int off = 32; off; off >>= 1) v = fmaxf(v, __shfl_down(v, off));
    __syncthreads();
    if ((threadIdx.x & 63) == 0) red[threadIdx.x >> 6] = v;
    __syncthreads();
    return fmaxf(fmaxf(red[0], red[1]), fmaxf(red[2], red[3]));
}

#define COLLECT(v, idx)                                                  \
    do {                                                                 \
        if ((v) >= SPEC_TH) {                                            \
            int p_ = atomicAdd(&s_candCount, 1);                         \
            if (p_ < CAP) { candVal[p_] = (v); candIdx[p_] = (idx); }    \
        }                                                                \
    } while (0)
#define COLLECT4(tv, base)                                               \
    do {                                                                 \
        COLLECT((tv).x, (base));                                         \
        COLLECT((tv).y, (base) + 1);                                     \
        COLLECT((tv).z, (base) + 2);                                     \
        COLLECT((tv).w, (base) + 3);                                     \
    } while (0)

__global__ __launch_bounds__(BLOCK, 8) void tcs_main(
    const float* __restrict__ S, const float* __restrict__ T,
    const int* __restrict__ L, float* __restrict__ acc, int V, int tokens)
{
    const int tok = blockIdx.x;
    if (tok >= tokens) return;
    const int tid = threadIdx.x;
    const size_t row = (size_t)tok * (size_t)V;
    const float* srow = S + row;
    const float* trow = T + row;

    __shared__ float candVal[CAP];
    __shared__ int   candIdx[CAP];
    __shared__ float selVal[128];
    __shared__ int   selIdx[128];
    __shared__ unsigned hist[NHIST];   // fallback only
    __shared__ unsigned chunk[64];     // fallback only
    __shared__ float red[4], redM[4], redS[4];
    __shared__ int s_candCount, s_selCount;
    __shared__ unsigned s_lowBound, s_countGE, s_cGT;
    __shared__ int s_shift;

    // Early label fetch (latency hidden under pass A).
    int lab = 0; bool valid = false; float sl = 0.0f;
    if (tid == 0) {
        s_candCount = 0;
        lab = L[tok];
        valid = (lab != IGNORE_INDEX);
        if (valid && lab >= 0 && lab < V) sl = srow[lab];
    }
    __syncthreads();

    // ---- Pass A: student online LSE (4 indep accumulators) + teacher
    //      speculative candidate collection. 8 float4 loads batched/iter
    //      for MLP; __launch_bounds__(,8) keeps 8 waves/SIMD at <=64 VGPR.
    float m0 = -INFINITY, m1 = -INFINITY, m2 = -INFINITY, m3 = -INFINITY;
    float s0 = 0.f, s1 = 0.f, s2 = 0.f, s3 = 0.f;
    const int V4 = V >> 2;
    const float4* s4 = (const float4*)srow;
    const float4* t4 = (const float4*)trow;

    int i = tid;
#pragma unroll 1
    for (; i + 3 * BLOCK < V4; i += 4 * BLOCK) {
        float4 sa = s4[i];
        float4 sb = s4[i + BLOCK];
        float4 sc = s4[i + 2 * BLOCK];
        float4 sd = s4[i + 3 * BLOCK];
        float4 ta = t4[i];
        float4 tb = t4[i + BLOCK];
        float4 tc = t4[i + 2 * BLOCK];
        float4 td = t4[i + 3 * BLOCK];
        lse_acc(m0, s0, sa.x); lse_acc(m1, s1, sa.y); lse_acc(m2, s2, sa.z); lse_acc(m3, s3, sa.w);
        lse_acc(m0, s0, sb.x); lse_acc(m1, s1, sb.y); lse_acc(m2, s2, sb.z); lse_acc(m3, s3, sb.w);
        lse_acc(m0, s0, sc.x); lse_acc(m1, s1, sc.y); lse_acc(m2, s2, sc.z); lse_acc(m3, s3, sc.w);
        lse_acc(m0, s0, sd.x); lse_acc(m1, s1, sd.y); lse_acc(m2, s2, sd.z); lse_acc(m3, s3, sd.w);
        COLLECT4(ta, i << 2);
        COLLECT4(tb, (i + BLOCK) << 2);
        COLLECT4(tc, (i + 2 * BLOCK) << 2);
        COLLECT4(td, (i + 3 * BLOCK) << 2);
    }
#pragma unroll 1
    for (; i < V4; i += BLOCK) {
        float4 sv = s4[i];
        float4 tv = t4[i];
        lse_acc(m0, s0, sv.x); lse_acc(m1, s1, sv.y); lse_acc(m2, s2, sv.z); lse_acc(m3, s3, sv.w);
        COLLECT4(tv, i << 2);
    }
    for (int j = (V4 << 2) + tid; j < V; j += BLOCK) {
        lse_acc(m0, s0, srow[j]);
        float tvx = trow[j];
        COLLECT(tvx, j);
    }

    // merge the 4 accumulators, then wave + block reduce
    {
        float mn = fmaxf(m0, m1); s0 = s0 * __expf(m0 - mn) + s1 * __expf(m1 - mn); m0 = mn;
        mn = fmaxf(m2, m3);       s2 = s2 * __expf(m2 - mn) + s3 * __expf(m3 - mn); m2 = mn;
        mn = fmaxf(m0, m2);       s0 = s0 * __expf(m0 - mn) + s2 * __expf(m2 - mn); m0 = mn;
    }
    for (int off = 32; off; off >>= 1) {
        float mo = __shfl_down(m0, off);
        float so = __shfl_down(s0, off);
        float mn = fmaxf(m0, mo);
        s0 = s0 * __expf(m0 - mn) + so * __expf(mo - mn);
        m0 = mn;
    }
    if ((tid & 63) == 0) { redM[tid >> 6] = m0; redS[tid >> 6] = s0; }
    __syncthreads();   // closes collection atomics + redM/redS writes

    float nll = 0.0f;
    if (tid == 0) {
        float mm = redM[0], ss = redS[0];
        for (int w = 1; w < 4; ++w) {
            float mn = fmaxf(mm, redM[w]);
            ss = ss * __expf(mm - mn) + redS[w] * __expf(redM[w] - mn);
            mm = mn;
        }
        nll = (mm + __logf(ss)) - sl;   // -log_softmax at label
    }

    const int M0 = s_candCount;
    const bool fast = (M0 >= KTOP && M0 <= CAP);   // block-uniform

    if (!fast) {
        // ---- exact radix-select fallback (arbitrary data) ----
        for (int b = tid; b < NHIST; b += BLOCK) hist[b] = 0;
        if (tid == 0) s_candCount = 0;
        __syncthreads();
        for (int p = tid; p < V; p += BLOCK)
            atomicAdd(&hist[key_of(trow[p]) >> 23], 1u);
        __syncthreads();
        if (tid < 64) {
            unsigned cs = 0;
            for (int b = tid * 8; b < tid * 8 + 8; ++b) cs += hist[b];
            chunk[tid] = cs;
        }
        __syncthreads();
        if (tid == 0) {
            unsigned accum = 0; int csel = 0;
            for (int c = 63; c >= 0; --c) {
                if (accum + chunk[c] >= (unsigned)KTOP) { csel = c; break; }
                accum += chunk[c];
            }
            int bsel = csel * 8;
            for (int b = csel * 8 + 7; b >= csel * 8; --b) {
                if (accum + hist[b] >= (unsigned)KTOP) { bsel = b; break; }
                accum += hist[b];
            }
            s_cGT = accum;
            s_countGE = accum + hist[bsel];
            s_lowBound = (unsigned)bsel << 23;
            s_shift = 23;
        }
        while (true) {
            __syncthreads();
            if (s_countGE <= (unsigned)CAP || s_shift == 0) break;
            const int shift = s_shift;
            const int nextShift = (shift >= 9) ? (shift - 9) : 0;
            const int nb = 1 << (shift - nextShift);
            const unsigned prefix = s_lowBound >> shift;
            const unsigned cGT_in = s_cGT;
            __syncthreads();
            for (int b = tid; b < nb; b += BLOCK) hist[b] = 0;
            __syncthreads();
            for (int p = tid; p < V; p += BLOCK) {
                unsigned key = key_of(trow[p]);
                if ((int)(key >> shift) == (int)prefix)
                    atomicAdd(&hist[(key >> nextShift) & (nb - 1)], 1u);
            }
            __syncthreads();
            if (tid == 0) {
                unsigned kRem = (unsigned)KTOP - cGT_in;
                unsigned accum = 0; int bsel = 0;
                for (int b = nb - 1; b >= 0; --b) {
                    if (accum + hist[b] >= kRem) { bsel = b; break; }
                    accum += hist[b];
                }
                s_cGT = cGT_in + accum;
                s_countGE = s_cGT + hist[bsel];
                s_lowBound |= (unsigned)bsel << nextShift;
                s_shift = nextShift;
            }
        }
        __syncthreads();
        const unsigned lowB = s_lowBound;
        for (int p = tid; p < V; p += BLOCK) {
            float v = trow[p];
            if (key_of(v) >= lowB) {
                int q = atomicAdd(&s_candCount, 1);
                if (q < CAP) { candVal[q] = v; candIdx[q] = p; }
            }
        }
        __syncthreads();
    }

    // ---- exact top-K among M candidates via O(M^2) ranking (idx tie-break) ----
    const int M = min(s_candCount, CAP);
    if (tid == 0) s_selCount = 0;
    __syncthreads();
    for (int c = tid; c < M; c += BLOCK) {
        float vc = candVal[c]; int ic = candIdx[c];
        int rank = 0;
        for (int j = 0; j < M; ++j) {
            float vj = candVal[j]; int ij = candIdx[j];
            if (vj > vc || (vj == vc && ij < ic)) ++rank;
        }
        if (rank < KTOP) {
            int p = atomicAdd(&s_selCount, 1);
            if (p < 128) { selVal[p] = vc; selIdx[p] = ic; }
        }
    }
    __syncthreads();
    const int n = min(s_selCount, 128);

    // ---- temperature KL over the selected top-K ----
    float x = -INFINITY, y = -INFINITY;
    if (tid < n) {
        x = selVal[tid] * (1.0f / TEMP);
        y = srow[selIdx[tid]] * (1.0f / TEMP);
    }
    float mx = block_max(x, red);
    float my = block_max(y, red);
    float ex = (tid < n) ? __expf(x - mx) : 0.0f;
    float Zt = block_sum(ex, red);
    float ey = (tid < n) ? __expf(y - my) : 0.0f;
    float Zs = block_sum(ey, red);
    float lZt = __logf(Zt), lZs = __logf(Zs);
    float kli = (tid < n) ? (ex / Zt) * ((x - mx - lZt) - (y - my - lZs)) : 0.0f;
    float kl = block_sum(kli, red);

    if (tid == 0 && valid) {
        atomicAdd(&acc[0], nll);
        atomicAdd(&acc[1], kl);
        atomicAdd(&acc[2], 1.0f);
    }
}

__global__ void tcs_finalize(const float* __restrict__ acc, float* __restrict__ out) {
    float cnt = fmaxf(acc[2], 1.0f);
    float ce = acc[0] / cnt;
    float tcs = acc[1] / cnt * (TEMP * TEMP);
    out[0] = ce + LAMBDA_TCS * tcs;
    out[1] = ce;
    out[2] = tcs;
    out[3] = 0.0f;
}

extern "C" void kernel_launch(void* const* d_in, const int* in_sizes, int n_in,
                              void* d_out, int out_size, void* d_ws, size_t ws_size,
                              hipStream_t stream) {
    const float* S = (const float*)d_in[0];
    const float* T = (const float*)d_in[1];
    const int* L = (const int*)d_in[2];
    const int tokens = in_sizes[2];
    const int V = in_sizes[0] / tokens;
    float* acc = (float*)d_ws;
    hipMemsetAsync(acc, 0, 4 * sizeof(float), stream);
    tcs_main<<<tokens, BLOCK, 0, stream>>>(S, T, L, acc, V, tokens);
    tcs_finalize<<<1, 1, 0, stream>>>(acc, (float*)d_out);
}